// Round 1
// baseline (717.910 us; speedup 1.0000x reference)
//
#include <hip/hip_runtime.h>
#include <math.h>

#define NPTS 262144

// -------------------- K1: gate + top-2 binning --------------------
__global__ __launch_bounds__(256) void gate_kernel(
    const float* __restrict__ coords,
    const float* __restrict__ fw, const float* __restrict__ fb,
    const float* __restrict__ gw1, const float* __restrict__ gb1,
    const float* __restrict__ ln_g, const float* __restrict__ ln_b,
    const float* __restrict__ gw2, const float* __restrict__ gb2,
    int* __restrict__ counts, int* __restrict__ buckets)
{
    __shared__ float s_fw[64 * 3];
    __shared__ float s_fb[64];
    __shared__ float s_gw1[64 * 64];
    __shared__ float s_gb1[64];
    __shared__ float s_lng[64];
    __shared__ float s_lnb[64];
    __shared__ float s_gw2[8 * 64];
    __shared__ float s_gb2[8];

    const int t = threadIdx.x;
    for (int i = t; i < 64 * 64; i += 256) s_gw1[i] = gw1[i];
    for (int i = t; i < 8 * 64; i += 256) s_gw2[i] = gw2[i];
    if (t < 192) s_fw[t] = fw[t];
    if (t < 64) { s_fb[t] = fb[t]; s_gb1[t] = gb1[t]; s_lng[t] = ln_g[t]; s_lnb[t] = ln_b[t]; }
    if (t < 8) s_gb2[t] = gb2[t];
    __syncthreads();

    const int n = blockIdx.x * 256 + t;
    const float c0 = coords[n * 3 + 0], c1 = coords[n * 3 + 1], c2 = coords[n * 3 + 2];

    float f[64];
#pragma unroll
    for (int j = 0; j < 64; j++)
        f[j] = s_fb[j] + c0 * s_fw[j * 3 + 0] + c1 * s_fw[j * 3 + 1] + c2 * s_fw[j * 3 + 2];

    float g[64];
    float mu = 0.f;
#pragma unroll
    for (int j = 0; j < 64; j++) {
        float a = s_gb1[j];
#pragma unroll
        for (int k = 0; k < 64; k += 4) {
            const float4 w = *(const float4*)&s_gw1[j * 64 + k];
            a += f[k] * w.x + f[k + 1] * w.y + f[k + 2] * w.z + f[k + 3] * w.w;
        }
        g[j] = a; mu += a;
    }
    mu *= (1.f / 64.f);
    float var = 0.f;
#pragma unroll
    for (int j = 0; j < 64; j++) { float d = g[j] - mu; var += d * d; }
    var *= (1.f / 64.f);
    const float rs = rsqrtf(var + 1e-5f);

    float logit[8];
#pragma unroll
    for (int e = 0; e < 8; e++) logit[e] = s_gb2[e];
#pragma unroll
    for (int k = 0; k < 64; k++) {
        const float gn = (g[k] - mu) * rs * s_lng[k] + s_lnb[k];
#pragma unroll
        for (int e = 0; e < 8; e++) logit[e] += gn * s_gw2[e * 64 + k];
    }

    // top-2 with reference tie semantics: selected iff logit >= (2nd largest with multiplicity)
    float m1 = logit[0]; int i1 = 0;
#pragma unroll
    for (int e = 1; e < 8; e++) if (logit[e] > m1) { m1 = logit[e]; i1 = e; }
    float m2 = -INFINITY;
#pragma unroll
    for (int e = 0; e < 8; e++) if (e != i1 && logit[e] > m2) m2 = logit[e];

#pragma unroll
    for (int e = 0; e < 8; e++) {
        if (logit[e] >= m2) {
            const int pos = atomicAdd(&counts[e], 1);
            buckets[e * NPTS + pos] = n;
        }
    }
}

// -------------------- K2: per-expert SIREN on its bucket --------------------
__global__ __launch_bounds__(256) void expert_kernel(
    const float* __restrict__ coords,
    const float* __restrict__ fw, const float* __restrict__ fb,
    const float* __restrict__ we0, const float* __restrict__ be0,
    const float* __restrict__ wm, const float* __restrict__ bm,
    const float* __restrict__ wl, const float* __restrict__ bl,
    const int* __restrict__ counts, const int* __restrict__ buckets,
    float* __restrict__ out)
{
    const int bpe = NPTS / 256;              // 1024 chunks per expert (worst case)
    const int e = blockIdx.x / bpe;
    const int chunk = blockIdx.x % bpe;
    const int cnt = counts[e];
    const int base = chunk * 256;
    if (base >= cnt) return;                 // uniform exit, before any barrier

    __shared__ float s_w0[4096];
    __shared__ float s_w1[4096];
    __shared__ float s_w2[4096];
    __shared__ float s_b0[64], s_b1[64], s_b2[64], s_wl[64], s_fb[64];
    __shared__ float s_fw[192];
    __shared__ float s_bl;

    const int t = threadIdx.x;
    {
        const float* p0 = we0 + e * 4096;
        const float* p1 = wm + (0 * 8 + e) * 4096;
        const float* p2 = wm + (1 * 8 + e) * 4096;
        for (int i = t; i < 4096; i += 256) { s_w0[i] = p0[i]; s_w1[i] = p1[i]; s_w2[i] = p2[i]; }
        if (t < 64) {
            s_b0[t] = be0[e * 64 + t];
            s_b1[t] = bm[(0 * 8 + e) * 64 + t];
            s_b2[t] = bm[(1 * 8 + e) * 64 + t];
            s_wl[t] = wl[e * 64 + t];
            s_fb[t] = fb[t];
        }
        if (t < 192) s_fw[t] = fw[t];
        if (t == 0) s_bl = bl[e];
    }
    __syncthreads();

    const int i = base + t;
    if (i >= cnt) return;
    const int n = buckets[e * NPTS + i];
    const float c0 = coords[n * 3 + 0], c1 = coords[n * 3 + 1], c2 = coords[n * 3 + 2];
    const float w0 = 22.5f + 45.0f * (float)e;   // W0S[e] = 0.5*45 + 45*e

    float A[64], B[64];
#pragma unroll
    for (int j = 0; j < 64; j++)
        A[j] = s_fb[j] + c0 * s_fw[j * 3 + 0] + c1 * s_fw[j * 3 + 1] + c2 * s_fw[j * 3 + 2];

    // layer 0: B = sin(w0 * (A @ W0^T + b0))
#pragma unroll
    for (int j = 0; j < 64; j++) {
        float a = s_b0[j];
#pragma unroll
        for (int k = 0; k < 64; k += 4) {
            const float4 w = *(const float4*)&s_w0[j * 64 + k];
            a += A[k] * w.x + A[k + 1] * w.y + A[k + 2] * w.z + A[k + 3] * w.w;
        }
        B[j] = __sinf(w0 * a);
    }
    // layer 1: A = sin(30 * (B @ W1^T + b1))
#pragma unroll
    for (int j = 0; j < 64; j++) {
        float a = s_b1[j];
#pragma unroll
        for (int k = 0; k < 64; k += 4) {
            const float4 w = *(const float4*)&s_w1[j * 64 + k];
            a += B[k] * w.x + B[k + 1] * w.y + B[k + 2] * w.z + B[k + 3] * w.w;
        }
        A[j] = __sinf(30.f * a);
    }
    // layer 2: B = sin(30 * (A @ W2^T + b2))
#pragma unroll
    for (int j = 0; j < 64; j++) {
        float a = s_b2[j];
#pragma unroll
        for (int k = 0; k < 64; k += 4) {
            const float4 w = *(const float4*)&s_w2[j * 64 + k];
            a += A[k] * w.x + A[k + 1] * w.y + A[k + 2] * w.z + A[k + 3] * w.w;
        }
        B[j] = __sinf(30.f * a);
    }
    float x = s_bl;
#pragma unroll
    for (int k = 0; k < 64; k++) x += B[k] * s_wl[k];
    atomicAdd(&out[n], x);
}

// -------------------- K3: aux loss --------------------
__global__ void aux_kernel(const int* __restrict__ counts, float* __restrict__ out)
{
    if (threadIdx.x == 0 && blockIdx.x == 0) {
        double s = 0.0;
        for (int e = 0; e < 8; e++) { const double c = (double)counts[e]; s += c * c; }
        out[NPTS] = (float)(8.0 * s / ((double)NPTS * (double)NPTS));
    }
}

extern "C" void kernel_launch(void* const* d_in, const int* in_sizes, int n_in,
                              void* d_out, int out_size, void* d_ws, size_t ws_size,
                              hipStream_t stream)
{
    const float* coords = (const float*)d_in[0];
    const float* fw  = (const float*)d_in[1];
    const float* fb  = (const float*)d_in[2];
    const float* gw1 = (const float*)d_in[3];
    const float* gb1 = (const float*)d_in[4];
    const float* ln_g = (const float*)d_in[5];
    const float* ln_b = (const float*)d_in[6];
    const float* gw2 = (const float*)d_in[7];
    const float* gb2 = (const float*)d_in[8];
    const float* we0 = (const float*)d_in[9];
    const float* be0 = (const float*)d_in[10];
    const float* wm  = (const float*)d_in[11];
    const float* bm  = (const float*)d_in[12];
    const float* wl  = (const float*)d_in[13];
    const float* bl  = (const float*)d_in[14];
    float* out = (float*)d_out;

    int* counts = (int*)d_ws;
    int* buckets = counts + 16;   // 64-byte aligned region for buckets[8][NPTS]

    hipMemsetAsync(counts, 0, 16 * sizeof(int), stream);
    hipMemsetAsync(d_out, 0, (size_t)(NPTS + 1) * sizeof(float), stream);

    gate_kernel<<<NPTS / 256, 256, 0, stream>>>(coords, fw, fb, gw1, gb1, ln_g, ln_b,
                                                gw2, gb2, counts, buckets);
    expert_kernel<<<8 * (NPTS / 256), 256, 0, stream>>>(coords, fw, fb, we0, be0, wm, bm,
                                                        wl, bl, counts, buckets, out);
    aux_kernel<<<1, 64, 0, stream>>>(counts, out);
}

// Round 2
// 207.005 us; speedup vs baseline: 3.4681x; 3.4681x over previous
//
#include <hip/hip_runtime.h>
#include <math.h>

#define NPTS 262144
#define NBLK (NPTS / 128)

typedef float f4v __attribute__((ext_vector_type(4)));
typedef short s8v __attribute__((ext_vector_type(8)));

static __device__ __forceinline__ unsigned short f2bf(float f) {
    unsigned u = __float_as_uint(f);
    u += 0x7fffu + ((u >> 16) & 1u);
    return (unsigned short)(u >> 16);
}
static __device__ __forceinline__ unsigned pack2(float lo, float hi) {
    return ((unsigned)f2bf(hi) << 16) | (unsigned)f2bf(lo);
}
static __device__ __forceinline__ float sinrev(float x) {   // sin(2*pi*x)
    return __builtin_amdgcn_sinf(x);
}

union BFrag { uint4 q; unsigned u[4]; s8v s; };

// ---------------- prep: pack A-fragments (pre-scaled bf16 weights) + scaled biases ----------------
// packA frag layout: [(e*3+l)*8 + tau*2+ks][lane][8 bf16], elem i of lane l:
//   row = 16*tau + (l&15), k = 32*ks + 4*(l>>4) + (i<4 ? i : i+12)
__global__ __launch_bounds__(256) void prep_kernel(
    const float* __restrict__ we0, const float* __restrict__ be0,
    const float* __restrict__ wm, const float* __restrict__ bm,
    uint4* __restrict__ packA, float* __restrict__ biasS)
{
    const int idx = blockIdx.x * 256 + threadIdx.x;
    const float PI2I = 0.15915494309189535f;
    if (idx < 12288) {
        const int l = idx & 63;
        const int fr = (idx >> 6) & 7;
        const int grp = idx >> 9;            // e*3 + ell
        const int e = grp / 3, ell = grp % 3;
        const int tau = fr >> 1, ks = fr & 1;
        const int g = l >> 4, m = l & 15;
        const int row = tau * 16 + m;
        const float scale = (ell == 0) ? (22.5f + 45.0f * (float)e) * PI2I : 30.0f * PI2I;
        const float* W = (ell == 0) ? (we0 + e * 4096) : (wm + ((ell - 1) * 8 + e) * 4096);
        unsigned short v[8];
#pragma unroll
        for (int i = 0; i < 8; i++) {
            const int k = 32 * ks + 4 * g + (i < 4 ? i : i + 12);
            v[i] = f2bf(W[row * 64 + k] * scale);
        }
        uint4 q;
        q.x = (unsigned)v[0] | ((unsigned)v[1] << 16);
        q.y = (unsigned)v[2] | ((unsigned)v[3] << 16);
        q.z = (unsigned)v[4] | ((unsigned)v[5] << 16);
        q.w = (unsigned)v[6] | ((unsigned)v[7] << 16);
        packA[idx] = q;
    } else if (idx < 12288 + 1536) {
        const int j = idx - 12288;           // (e*3+ell)*64 + r
        const int r = j & 63;
        const int grp = j >> 6;
        const int e = grp / 3, ell = grp % 3;
        const float scale = (ell == 0) ? (22.5f + 45.0f * (float)e) * PI2I : 30.0f * PI2I;
        const float b = (ell == 0) ? be0[e * 64 + r] : bm[((ell - 1) * 8 + e) * 64 + r];
        biasS[j] = b * scale;
    }
}

// ---------------- fused main kernel: gate (fp32 scalar) + dense MFMA experts ----------------
__global__ __launch_bounds__(256) void moe_kernel(
    const float* __restrict__ coords,
    const float* __restrict__ fw, const float* __restrict__ fb,
    const float* __restrict__ gw1, const float* __restrict__ gb1,
    const float* __restrict__ lng, const float* __restrict__ lnb,
    const float* __restrict__ gw2, const float* __restrict__ gb2,
    const float* __restrict__ wl, const float* __restrict__ bl,
    const uint4* __restrict__ packA, const float* __restrict__ biasS,
    float* __restrict__ out, int* __restrict__ blkcnt)
{
    __shared__ float s_fw[192], s_fb[64], s_gb1[64], s_lng[64], s_lnb[64], s_gb2[8];
    __shared__ float s_gw1[4096];
    __shared__ float s_gw2[512];
    __shared__ float s_wl[512];
    __shared__ float s_bl[8];
    __shared__ float s_bias[1536];
    __shared__ unsigned short s_ft[128 * 68];   // row stride 136 B (bank-friendly)
    __shared__ unsigned char s_sel[128];
    __shared__ int s_cnt[8];

    const int t = threadIdx.x;
    for (int i = t; i < 4096; i += 256) s_gw1[i] = gw1[i];
    for (int i = t; i < 1536; i += 256) s_bias[i] = biasS[i];
    for (int i = t; i < 512; i += 256) { s_gw2[i] = gw2[i]; s_wl[i] = wl[i]; }
    if (t < 192) s_fw[t] = fw[t];
    if (t < 64) { s_fb[t] = fb[t]; s_gb1[t] = gb1[t]; s_lng[t] = lng[t]; s_lnb[t] = lnb[t]; }
    if (t < 8) { s_gb2[t] = gb2[t]; s_bl[t] = bl[t]; s_cnt[t] = 0; }
    __syncthreads();

    // ======== gate phase (fp32, pair-split: 2 threads per point) ========
    const int half = t & 1;
    const int p = t >> 1;                       // block-local point 0..127
    const int n = blockIdx.x * 128 + p;
    float f[64];
    {
        const float c0 = coords[n * 3], c1 = coords[n * 3 + 1], c2 = coords[n * 3 + 2];
#pragma unroll
        for (int j = 0; j < 64; j++)
            f[j] = s_fb[j] + c0 * s_fw[j * 3] + c1 * s_fw[j * 3 + 1] + c2 * s_fw[j * 3 + 2];
    }
    // stash feature (bf16) for the MFMA phase; each half writes its 32 features
    {
#pragma unroll
        for (int q = 0; q < 8; q++) {
            const int fbase = 32 * half + q * 4;
            uint2 w;
            w.x = pack2(f[fbase], f[fbase + 1]);
            w.y = pack2(f[fbase + 2], f[fbase + 3]);
            *(uint2*)((char*)s_ft + p * 136 + fbase * 2) = w;
        }
    }
    float gg[32];
    float mupart = 0.f;
#pragma unroll
    for (int j = 0; j < 32; j++) {
        const int row = j + 32 * half;
        float a = s_gb1[row];
#pragma unroll
        for (int k = 0; k < 64; k += 4) {
            const float4 w = *(const float4*)&s_gw1[row * 64 + k];
            a += f[k] * w.x + f[k + 1] * w.y + f[k + 2] * w.z + f[k + 3] * w.w;
        }
        gg[j] = a; mupart += a;
    }
    const float mu = (mupart + __shfl_xor(mupart, 1, 64)) * (1.f / 64.f);
    float vpart = 0.f;
#pragma unroll
    for (int j = 0; j < 32; j++) { const float d = gg[j] - mu; vpart += d * d; }
    const float var = (vpart + __shfl_xor(vpart, 1, 64)) * (1.f / 64.f);
    const float rs = rsqrtf(var + 1e-5f);
    float logit[8];
#pragma unroll
    for (int e = 0; e < 8; e++) logit[e] = half ? 0.f : s_gb2[e];
#pragma unroll
    for (int j = 0; j < 32; j++) {
        const int row = j + 32 * half;
        const float gn = (gg[j] - mu) * rs * s_lng[row] + s_lnb[row];
#pragma unroll
        for (int e = 0; e < 8; e++) logit[e] += gn * s_gw2[e * 64 + row];
    }
#pragma unroll
    for (int e = 0; e < 8; e++) logit[e] += __shfl_xor(logit[e], 1, 64);
    // top-2 (reference tie semantics: selected iff logit >= 2nd largest)
    float m1 = logit[0]; int i1 = 0;
#pragma unroll
    for (int e = 1; e < 8; e++) if (logit[e] > m1) { m1 = logit[e]; i1 = e; }
    float m2 = -INFINITY;
#pragma unroll
    for (int e = 0; e < 8; e++) if (e != i1 && logit[e] > m2) m2 = logit[e];
    unsigned mbits = 0;
#pragma unroll
    for (int e = 0; e < 8; e++) if (logit[e] >= m2) mbits |= 1u << e;
    if (!half) s_sel[p] = (unsigned char)mbits;
#pragma unroll
    for (int e = 0; e < 8; e++) {
        const unsigned long long bal = __ballot((!half) && ((mbits >> e) & 1u));
        if ((t & 63) == 0) atomicAdd(&s_cnt[e], __popcll(bal));
    }
    __syncthreads();
    if (t < 8) blkcnt[blockIdx.x * 8 + t] = s_cnt[t];

    // ======== expert phase: dense MFMA, activations live in registers ========
    const int lane = t & 63;
    const int wv = t >> 6;
    const int g = lane >> 4, c = lane & 15;
    const int p0 = wv * 32 + c;                 // nt = 0
    const int p1 = p0 + 16;                     // nt = 1
    const unsigned sel0 = s_sel[p0], sel1 = s_sel[p1];
    float accout0 = 0.f, accout1 = 0.f;

#pragma unroll 1
    for (int e = 0; e < 8; e++) {
        BFrag B0[2], B1[2];
        // layer-0 B fragments straight from staged features
#pragma unroll
        for (int ks = 0; ks < 2; ks++) {
            const int fb0 = 32 * ks + 4 * g;
            const uint2 lo0 = *(const uint2*)((const char*)s_ft + p0 * 136 + fb0 * 2);
            const uint2 hi0 = *(const uint2*)((const char*)s_ft + p0 * 136 + (fb0 + 16) * 2);
            B0[ks].u[0] = lo0.x; B0[ks].u[1] = lo0.y; B0[ks].u[2] = hi0.x; B0[ks].u[3] = hi0.y;
            const uint2 lo1 = *(const uint2*)((const char*)s_ft + p1 * 136 + fb0 * 2);
            const uint2 hi1 = *(const uint2*)((const char*)s_ft + p1 * 136 + (fb0 + 16) * 2);
            B1[ks].u[0] = lo1.x; B1[ks].u[1] = lo1.y; B1[ks].u[2] = hi1.x; B1[ks].u[3] = hi1.y;
        }
#pragma unroll
        for (int ell = 0; ell < 3; ell++) {
            f4v acc0[4], acc1[4];
#pragma unroll
            for (int tau = 0; tau < 4; tau++) {
#pragma unroll
                for (int j = 0; j < 4; j++) {
                    const float b = s_bias[(e * 3 + ell) * 64 + tau * 16 + 4 * g + j];
                    acc0[tau][j] = b; acc1[tau][j] = b;
                }
            }
            const uint4* Ab = packA + (size_t)((e * 3 + ell) * 8) * 64 + lane;
#pragma unroll
            for (int tau = 0; tau < 4; tau++) {
                BFrag A0, A1;
                A0.q = Ab[(tau * 2 + 0) * 64];
                A1.q = Ab[(tau * 2 + 1) * 64];
                acc0[tau] = __builtin_amdgcn_mfma_f32_16x16x32_bf16(A0.s, B0[0].s, acc0[tau], 0, 0, 0);
                acc0[tau] = __builtin_amdgcn_mfma_f32_16x16x32_bf16(A1.s, B0[1].s, acc0[tau], 0, 0, 0);
                acc1[tau] = __builtin_amdgcn_mfma_f32_16x16x32_bf16(A0.s, B1[0].s, acc1[tau], 0, 0, 0);
                acc1[tau] = __builtin_amdgcn_mfma_f32_16x16x32_bf16(A1.s, B1[1].s, acc1[tau], 0, 0, 0);
            }
            if (ell < 2) {
                // sin + repack: D registers become next layer's B fragments (no LDS bounce)
#pragma unroll
                for (int ks = 0; ks < 2; ks++) {
                    B0[ks].u[0] = pack2(sinrev(acc0[2 * ks][0]), sinrev(acc0[2 * ks][1]));
                    B0[ks].u[1] = pack2(sinrev(acc0[2 * ks][2]), sinrev(acc0[2 * ks][3]));
                    B0[ks].u[2] = pack2(sinrev(acc0[2 * ks + 1][0]), sinrev(acc0[2 * ks + 1][1]));
                    B0[ks].u[3] = pack2(sinrev(acc0[2 * ks + 1][2]), sinrev(acc0[2 * ks + 1][3]));
                    B1[ks].u[0] = pack2(sinrev(acc1[2 * ks][0]), sinrev(acc1[2 * ks][1]));
                    B1[ks].u[1] = pack2(sinrev(acc1[2 * ks][2]), sinrev(acc1[2 * ks][3]));
                    B1[ks].u[2] = pack2(sinrev(acc1[2 * ks + 1][0]), sinrev(acc1[2 * ks + 1][1]));
                    B1[ks].u[3] = pack2(sinrev(acc1[2 * ks + 1][2]), sinrev(acc1[2 * ks + 1][3]));
                }
            } else {
                // final sin + dot with wl, reduce over feature groups (lanes ^16, ^32)
                float px0 = 0.f, px1 = 0.f;
#pragma unroll
                for (int tau = 0; tau < 4; tau++) {
#pragma unroll
                    for (int j = 0; j < 4; j++) {
                        const float wlv = s_wl[e * 64 + tau * 16 + 4 * g + j];
                        px0 += sinrev(acc0[tau][j]) * wlv;
                        px1 += sinrev(acc1[tau][j]) * wlv;
                    }
                }
                px0 += __shfl_xor(px0, 16, 64); px0 += __shfl_xor(px0, 32, 64);
                px1 += __shfl_xor(px1, 16, 64); px1 += __shfl_xor(px1, 32, 64);
                const float x0 = px0 + s_bl[e];
                const float x1 = px1 + s_bl[e];
                if ((sel0 >> e) & 1u) accout0 += x0;
                if ((sel1 >> e) & 1u) accout1 += x1;
            }
        }
    }
    if (g == 0) {
        out[blockIdx.x * 128 + p0] = accout0;
        out[blockIdx.x * 128 + p1] = accout1;
    }
}

// ---------------- aux loss ----------------
__global__ __launch_bounds__(256) void aux_kernel(const int* __restrict__ blkcnt, float* __restrict__ out)
{
    __shared__ int s_part[256];
    const int t = threadIdx.x;
    const int e = t & 7;
    int sum = 0;
    for (int b = t >> 3; b < NBLK; b += 32) sum += blkcnt[b * 8 + e];
    s_part[t] = sum;
    __syncthreads();
    if (t < 8) {
        int cc = 0;
        for (int i = t; i < 256; i += 8) cc += s_part[i];
        s_part[t] = cc;
    }
    __syncthreads();
    if (t == 0) {
        double s = 0.0;
        for (int e2 = 0; e2 < 8; e2++) { const double cd = (double)s_part[e2]; s += cd * cd; }
        out[NPTS] = (float)(8.0 * s / ((double)NPTS * (double)NPTS));
    }
}

extern "C" void kernel_launch(void* const* d_in, const int* in_sizes, int n_in,
                              void* d_out, int out_size, void* d_ws, size_t ws_size,
                              hipStream_t stream)
{
    const float* coords = (const float*)d_in[0];
    const float* fw  = (const float*)d_in[1];
    const float* fb  = (const float*)d_in[2];
    const float* gw1 = (const float*)d_in[3];
    const float* gb1 = (const float*)d_in[4];
    const float* lng = (const float*)d_in[5];
    const float* lnb = (const float*)d_in[6];
    const float* gw2 = (const float*)d_in[7];
    const float* gb2 = (const float*)d_in[8];
    const float* we0 = (const float*)d_in[9];
    const float* be0 = (const float*)d_in[10];
    const float* wm  = (const float*)d_in[11];
    const float* bm  = (const float*)d_in[12];
    const float* wl  = (const float*)d_in[13];
    const float* bl  = (const float*)d_in[14];
    float* out = (float*)d_out;

    uint4* packA = (uint4*)d_ws;                                  // 196608 B
    float* biasS = (float*)((char*)d_ws + 196608);                // 6144 B
    int* blkcnt  = (int*)((char*)d_ws + 202752);                  // NBLK*8*4 B

    prep_kernel<<<54, 256, 0, stream>>>(we0, be0, wm, bm, packA, biasS);
    moe_kernel<<<NBLK, 256, 0, stream>>>(coords, fw, fb, gw1, gb1, lng, lnb, gw2, gb2,
                                         wl, bl, packA, biasS, out, blkcnt);
    aux_kernel<<<1, 256, 0, stream>>>(blkcnt, out);
}